// Round 13
// baseline (225.859 us; speedup 1.0000x reference)
//
#include <hip/hip_runtime.h>
#include <hip/hip_bf16.h>

#define BB 8192
#define TT 64
#define L2E 1.44269504088896f

typedef __attribute__((ext_vector_type(8))) short bf16x8;
typedef __attribute__((ext_vector_type(4))) float f32x4;

__device__ __forceinline__ float exp2g(float x) { return __builtin_amdgcn_exp2f(x); }
__device__ __forceinline__ float rcpg(float x)  { return __builtin_amdgcn_rcpf(x); }
__device__ __forceinline__ short f2bf_s(float x) {
  __hip_bfloat16 b = __float2bfloat16(x);
  return *reinterpret_cast<short*>(&b);
}
// acts[row][k], k in [0,512): e_buf0, e_buf1, h_buf0, h_buf1. 16B-granule XOR swizzle.
__device__ __forceinline__ int aidx(int row, int k) {
  return row * 512 + ((((k >> 3) ^ (row & 7))) << 3) + (k & 7);
}

// ---- 1+2. fused: weights -> bf16 B-fragments (exp2-prescaled) AND input moments ----
__global__ void prep_stats_kernel(const float* __restrict__ Wih, const float* __restrict__ Whh,
                                  const float* __restrict__ bih, const float* __restrict__ bhh,
                                  const float* __restrict__ Wout,
                                  short* __restrict__ Wcb, short* __restrict__ Woutb,
                                  float* __restrict__ bc,
                                  const float* __restrict__ x, float* __restrict__ stats) {
  if (blockIdx.x < 67) {
    int idx = blockIdx.x * 256 + threadIdx.x;   // 17152 total
    if (idx < 16384) {
      int l = idx & 63, f = idx >> 6;
      int kt = f >> 5, nt = f & 31;
      int k0 = kt * 32 + ((l >> 4) << 3);
      int col = nt * 16 + (l & 15);
      int gate = col >> 7;
      float s = (gate == 2) ? (2.f * L2E) : (-L2E);
      const float* src = (k0 < 128) ? (Wih + col * 128 + k0) : (Whh + col * 128 + (k0 - 128));
      bf16x8 v;
      #pragma unroll
      for (int e = 0; e < 8; e++) v[e] = f2bf_s(src[e] * s);
      *(bf16x8*)(Wcb + (size_t)idx * 8) = v;
    } else if (idx < 16640) {
      int i2 = idx - 16384;
      int l = i2 & 63, f = i2 >> 6;              // f = kyt
      int k0 = f * 32 + ((l >> 4) << 3);
      int col = l & 15;
      bf16x8 v;
      #pragma unroll
      for (int e = 0; e < 8; e++)
        v[e] = (col < 5) ? f2bf_s(Wout[col * 128 + k0 + e]) : (short)0;
      *(bf16x8*)(Woutb + (size_t)i2 * 8) = v;
    } else {
      int i3 = idx - 16640;
      int gate = i3 >> 7;
      float s = (gate == 2) ? (2.f * L2E) : (-L2E);
      bc[i3] = (bih[i3] + bhh[i3]) * s;
    }
  } else {
    int t = blockIdx.x - 67, tid = threadIdx.x;
    float s0=0, s1=0, s2=0, s3=0, s4=0;
    for (int b = tid; b < BB; b += 256) {
      const float* p = x + ((size_t)b * TT + t) * 2;
      float x0 = p[0], x1 = p[1];
      s0 += x0; s1 += x1; s2 += x0*x0; s3 += x0*x1; s4 += x1*x1;
    }
    __shared__ float red[4][5];
    int lane = tid & 63, w = tid >> 6;
    #pragma unroll
    for (int off = 32; off > 0; off >>= 1) {
      s0 += __shfl_down(s0, off); s1 += __shfl_down(s1, off);
      s2 += __shfl_down(s2, off); s3 += __shfl_down(s3, off); s4 += __shfl_down(s4, off);
    }
    if (lane == 0) { red[w][0]=s0; red[w][1]=s1; red[w][2]=s2; red[w][3]=s3; red[w][4]=s4; }
    __syncthreads();
    if (tid < 5) stats[t*5 + tid] = red[0][tid] + red[1][tid] + red[2][tid] + red[3][tid];
  }
}

// ---- 3. fold input-BN + embed Linear + per-step embed-BN into A0/A1/C ----
__global__ void coef_kernel(const float* __restrict__ stats,
                            const float* __restrict__ Wemb, const float* __restrict__ bemb,
                            const float* __restrict__ ing, const float* __restrict__ inb,
                            const float* __restrict__ eg, const float* __restrict__ eb,
                            float* __restrict__ A0, float* __restrict__ A1, float* __restrict__ Ct) {
  __shared__ float st[64][5];
  __shared__ float glob[4];
  int tid = threadIdx.x;  // 128
  for (int i = tid; i < 320; i += 128) st[i / 5][i % 5] = stats[i];
  __syncthreads();
  if (tid == 0) {
    float S0=0, S1=0, S00=0, S11=0;
    for (int t = 0; t < 64; t++) { S0+=st[t][0]; S1+=st[t][1]; S00+=st[t][2]; S11+=st[t][4]; }
    float inv_n = 1.f / (float)(BB * TT);
    float M0 = S0*inv_n, M1 = S1*inv_n;
    float V0 = S00*inv_n - M0*M0, V1 = S11*inv_n - M1*M1;
    float P0 = rsqrtf(V0 + 1e-5f) * ing[0];
    float P1 = rsqrtf(V1 + 1e-5f) * ing[1];
    glob[0]=P0; glob[1]=P1; glob[2]=inb[0]-M0*P0; glob[3]=inb[1]-M1*P1;
  }
  __syncthreads();
  float P0=glob[0], P1=glob[1], Q0=glob[2], Q1=glob[3];
  int j = tid;
  float w0 = Wemb[j*2], w1 = Wemb[j*2+1];
  float a0 = P0*w0, a1 = P1*w1;
  float cj = Q0*w0 + Q1*w1 + bemb[j];
  float gam = eg[j], bet = eb[j];
  float invB = 1.f / (float)BB;
  for (int t = 0; t < 64; t++) {
    float m0 = st[t][0]*invB, m1 = st[t][1]*invB;
    float v00 = st[t][2]*invB - m0*m0;
    float v01 = st[t][3]*invB - m0*m1;
    float v11 = st[t][4]*invB - m1*m1;
    float mean = a0*m0 + a1*m1 + cj;
    float var  = a0*a0*v00 + 2.f*a0*a1*v01 + a1*a1*v11;
    float G = rsqrtf(var + 1e-5f) * gam;
    A0[t*128 + j] = G * a0;
    A1[t*128 + j] = G * a1;
    Ct[t*128 + j] = G * cj + (bet - mean * G);
  }
}

// write e(t) for row er, granule cg, into e-buffer (t&1)
__device__ __forceinline__ void write_e(short* acts_s,
                                        const float* __restrict__ A0, const float* __restrict__ A1,
                                        const float* __restrict__ Ct,
                                        int t, int er, int cg, const float* __restrict__ xs) {
  const float* a0p = A0 + t*128 + cg*8;
  const float* a1p = A1 + t*128 + cg*8;
  const float* ccp = Ct + t*128 + cg*8;
  const float4 a0a = *(const float4*)a0p, a0b = *(const float4*)(a0p + 4);
  const float4 a1a = *(const float4*)a1p, a1b = *(const float4*)(a1p + 4);
  const float4 cta = *(const float4*)ccp, ctb = *(const float4*)(ccp + 4);
  float x0 = xs[er * 128 + t * 2], x1 = xs[er * 128 + t * 2 + 1];
  bf16x8 v;
  v[0] = f2bf_s(fmaxf(fmaf(a0a.x, x0, fmaf(a1a.x, x1, cta.x)), 0.f));
  v[1] = f2bf_s(fmaxf(fmaf(a0a.y, x0, fmaf(a1a.y, x1, cta.y)), 0.f));
  v[2] = f2bf_s(fmaxf(fmaf(a0a.z, x0, fmaf(a1a.z, x1, cta.z)), 0.f));
  v[3] = f2bf_s(fmaxf(fmaf(a0a.w, x0, fmaf(a1a.w, x1, cta.w)), 0.f));
  v[4] = f2bf_s(fmaxf(fmaf(a0b.x, x0, fmaf(a1b.x, x1, ctb.x)), 0.f));
  v[5] = f2bf_s(fmaxf(fmaf(a0b.y, x0, fmaf(a1b.y, x1, ctb.y)), 0.f));
  v[6] = f2bf_s(fmaxf(fmaf(a0b.z, x0, fmaf(a1b.z, x1, ctb.z)), 0.f));
  v[7] = f2bf_s(fmaxf(fmaf(a0b.w, x0, fmaf(a1b.w, x1, ctb.w)), 0.f));
  int gk = (t & 1) * 16 + cg;
  *(bf16x8*)&acts_s[er * 512 + ((gk ^ (er & 7)) << 3)] = v;
}

// ---- 4. MFMA recurrence: R12 structure, mt-major MFMA ordering for pipe overlap ----
__launch_bounds__(512, 1)
__global__ void lstm_kernel(const float* __restrict__ x,
                            const float* __restrict__ A0, const float* __restrict__ A1,
                            const float* __restrict__ Ctab,
                            const short* __restrict__ Wcb, const float* __restrict__ bc,
                            const short* __restrict__ Woutb, const float* __restrict__ bout,
                            float* __restrict__ outy, float* __restrict__ hout,
                            float* __restrict__ cout) {
  __shared__ __align__(16) short acts_s[32 * 512];  // [row][k] swizzled, dbuf e,h
  __shared__ __align__(16) float xs[32 * 128];      // [row][t*2+{0,1}]

  const int tid  = threadIdx.x;
  const int lane = tid & 63;
  const int w    = tid >> 6;        // wave 0..7 -> col slice w*16 of each gate
  const int row0 = blockIdx.x * 32;
  const int cl   = lane & 15;       // col within slice / C-tile col / A-frag row
  const int lq   = lane >> 4;       // lane quad
  const int er   = tid >> 4;        // e-writer row 0..31
  const int cg   = tid & 15;        // e-writer col granule

  // preload x for this block's 32 rows
  {
    const float4* src = (const float4*)(x + (size_t)row0 * 128);
    float4* dst = (float4*)xs;
    dst[tid]       = src[tid];
    dst[tid + 512] = src[tid + 512];
  }

  // per-gate scaled biases (acc init values)
  float bgs[4];
  #pragma unroll
  for (int g = 0; g < 4; g++) bgs[g] = bc[g * 128 + w * 16 + cl];
  const float bov = (cl < 5) ? bout[cl] : 0.f;

  // gate weights resident in VGPRs: 32 fragments = 128 VGPRs
  bf16x8 wreg[8][4];
  {
    const bf16x8* wptr = (const bf16x8*)Wcb;
    #pragma unroll
    for (int kt = 0; kt < 8; kt++)
      #pragma unroll
      for (int g = 0; g < 4; g++)
        wreg[kt][g] = wptr[(size_t)(kt * 32 + g * 8 + w) * 64 + lane];
  }
  bf16x8 wof[4];
  if ((w & 3) == 0) {               // waves 0 and 4 run the y-projection
    #pragma unroll
    for (int kyt = 0; kyt < 4; kyt++)
      wof[kyt] = *(const bf16x8*)(Woutb + (size_t)(kyt * 64 + lane) * 8);
  }

  __syncthreads();  // xs ready

  // init: e(0) -> e-buf 0; h(-1)=0 -> h-buf 1
  write_e(acts_s, A0, A1, Ctab, 0, er, cg, xs);
  {
    bf16x8 z = (bf16x8)0;
    int gk = 32 + 16 + cg;          // h-buf 1
    *(bf16x8*)&acts_s[er * 512 + ((gk ^ (er & 7)) << 3)] = z;
  }

  f32x4 cstate[2] = {{0.f,0.f,0.f,0.f},{0.f,0.f,0.f,0.f}};
  float hl[2][4];

  #pragma unroll 1
  for (int t = 0; t < TT; t++) {
    __syncthreads();                 // step t-1 writes visible; all t-1 reads done
    const int ebuf = t & 1;          // e(t)
    const int hbuf = (t + 1) & 1;    // h(t-1)

    // y(t-1) = h(t-1) @ Wout^T + bout  (waves 0,4)
    if ((w & 3) == 0 && t > 0) {
      int mty = w >> 2;
      int row = mty * 16 + cl;
      f32x4 ya = (f32x4){0.f,0.f,0.f,0.f};
      #pragma unroll
      for (int kyt = 0; kyt < 4; kyt++) {
        int k = 256 + hbuf * 128 + (kyt * 4 + lq) * 8;
        bf16x8 ah = *(const bf16x8*)&acts_s[aidx(row, k)];
        ya = __builtin_amdgcn_mfma_f32_16x16x32_bf16(ah, wof[kyt], ya, 0, 0, 0);
      }
      if (cl < 5) {
        #pragma unroll
        for (int q = 0; q < 4; q++) {
          int brow = row0 + mty * 16 + lq * 4 + q;
          outy[((size_t)brow * TT + (t - 1)) * 5 + cl] = ya[q] + bov;
        }
      }
    }

    // gates = [e(t) | h(t-1)] @ Wc — mt-MAJOR chains so acc[.][0] completes early
    f32x4 acc[4][2];
    #pragma unroll
    for (int g = 0; g < 4; g++)
      #pragma unroll
      for (int mt = 0; mt < 2; mt++)
        acc[g][mt] = (f32x4){bgs[g], bgs[g], bgs[g], bgs[g]};

    #pragma unroll
    for (int kt = 0; kt < 8; kt++) {          // chain mt=0 (rows cl)
      int k = (kt < 4) ? (ebuf * 128 + (kt * 4 + lq) * 8)
                       : (256 + hbuf * 128 + ((kt - 4) * 4 + lq) * 8);
      bf16x8 a0 = *(const bf16x8*)&acts_s[aidx(cl, k)];
      #pragma unroll
      for (int g = 0; g < 4; g++)
        acc[g][0] = __builtin_amdgcn_mfma_f32_16x16x32_bf16(a0, wreg[kt][g], acc[g][0], 0, 0, 0);
    }
    #pragma unroll
    for (int kt = 0; kt < 8; kt++) {          // chain mt=1 (rows 16+cl)
      int k = (kt < 4) ? (ebuf * 128 + (kt * 4 + lq) * 8)
                       : (256 + hbuf * 128 + ((kt - 4) * 4 + lq) * 8);
      bf16x8 a1 = *(const bf16x8*)&acts_s[aidx(16 + cl, k)];
      #pragma unroll
      for (int g = 0; g < 4; g++)
        acc[g][1] = __builtin_amdgcn_mfma_f32_16x16x32_bf16(a1, wreg[kt][g], acc[g][1], 0, 0, 0);
    }

    // dependency-free VALU into the mt=1 MFMA shadow: e(t+1)
    if (t < TT - 1)
      write_e(acts_s, A0, A1, Ctab, t + 1, er, cg, xs);

    // elementwise mt=0 (waits only on acc[.][0]), then mt=1
    #pragma unroll
    for (int mt = 0; mt < 2; mt++) {
      #pragma unroll
      for (int q = 0; q < 4; q++) {
        float Ei = exp2g(acc[0][mt][q]);          // e^{-i}
        float Ef = exp2g(acc[1][mt][q]);          // e^{-f}
        float Eg = exp2g(acc[2][mt][q]);          // e^{2g}
        float Eo = exp2g(acc[3][mt][q]);          // e^{-o}
        float di = 1.f + Ei, df = 1.f + Ef, dg = 1.f + Eg;
        float p  = di * dg;
        // cn = c/df + (Eg-1)/p  ==  (c*p + (Eg-1)*df) * rcp(df*p)
        float num = fmaf(cstate[mt][q], p, (Eg - 1.f) * df);
        float cn  = num * rcpg(df * p);
        cstate[mt][q] = cn;
        float Ec = exp2g(cn * (2.f * L2E));       // e^{2c}
        float hn = (Ec - 1.f) * rcpg((1.f + Eo) * (1.f + Ec));  // sig(o)*tanh(c)
        hl[mt][q] = hn;
        int row = mt * 16 + lq * 4 + q;
        int k   = 256 + (t & 1) * 128 + w * 16 + cl;
        acts_s[aidx(row, k)] = f2bf_s(hn);
      }
    }
  }

  __syncthreads();                   // h(TT-1) visible
  if ((w & 3) == 0) {                // final y(TT-1)
    int mty = w >> 2;
    int row = mty * 16 + cl;
    f32x4 ya = (f32x4){0.f,0.f,0.f,0.f};
    #pragma unroll
    for (int kyt = 0; kyt < 4; kyt++) {
      int k = 256 + ((TT - 1) & 1) * 128 + (kyt * 4 + lq) * 8;
      bf16x8 ah = *(const bf16x8*)&acts_s[aidx(row, k)];
      ya = __builtin_amdgcn_mfma_f32_16x16x32_bf16(ah, wof[kyt], ya, 0, 0, 0);
    }
    if (cl < 5) {
      #pragma unroll
      for (int q = 0; q < 4; q++) {
        int brow = row0 + mty * 16 + lq * 4 + q;
        outy[((size_t)brow * TT + (TT - 1)) * 5 + cl] = ya[q] + bov;
      }
    }
  }

  // final h, c
  #pragma unroll
  for (int mt = 0; mt < 2; mt++) {
    #pragma unroll
    for (int q = 0; q < 4; q++) {
      int brow = row0 + mt * 16 + lq * 4 + q;
      int col  = w * 16 + cl;
      hout[(size_t)brow * 128 + col] = hl[mt][q];
      cout[(size_t)brow * 128 + col] = cstate[mt][q];
    }
  }
}

// ---- 5. per-(t,k) output BN partial stats (256 blocks = full chip) ----
__global__ void ostats_kernel(const float* __restrict__ outy, float* __restrict__ ostp) {
  int t = blockIdx.x >> 2, part = blockIdx.x & 3;
  int tid = threadIdx.x;
  float s[5] = {0,0,0,0,0}, s2[5] = {0,0,0,0,0};
  int b0 = part * 2048;
  for (int b = b0 + tid; b < b0 + 2048; b += 256) {
    const float* p = outy + ((size_t)b * TT + t) * 5;
    #pragma unroll
    for (int k = 0; k < 5; k++) { float v = p[k]; s[k] += v; s2[k] += v*v; }
  }
  __shared__ float red[4][10];
  int lane = tid & 63, w = tid >> 6;
  #pragma unroll
  for (int off = 32; off > 0; off >>= 1) {
    #pragma unroll
    for (int k = 0; k < 5; k++) {
      s[k]  += __shfl_down(s[k], off);
      s2[k] += __shfl_down(s2[k], off);
    }
  }
  if (lane == 0) {
    #pragma unroll
    for (int k = 0; k < 5; k++) { red[w][k] = s[k]; red[w][5+k] = s2[k]; }
  }
  __syncthreads();
  if (tid < 10) ostp[blockIdx.x * 10 + tid] = red[0][tid]+red[1][tid]+red[2][tid]+red[3][tid];
}

// ---- 6. fused finalize + normalize: each block recomputes sc/sh in LDS ----
__global__ void onorm_kernel(float* __restrict__ outy, const float* __restrict__ ostp,
                             const float* __restrict__ og, const float* __restrict__ ob) {
  __shared__ float sc[320], sh[320];
  int tid = threadIdx.x;
  const float invB = 1.f / (float)BB;
  for (int i = tid; i < 320; i += 256) {
    int t = i / 5, k = i - t * 5;
    float m  = (ostp[(t*4+0)*10+k]   + ostp[(t*4+1)*10+k]   + ostp[(t*4+2)*10+k]   + ostp[(t*4+3)*10+k]) * invB;
    float s2 = (ostp[(t*4+0)*10+5+k] + ostp[(t*4+1)*10+5+k] + ostp[(t*4+2)*10+5+k] + ostp[(t*4+3)*10+5+k]) * invB;
    float v = s2 - m * m;
    float scale = rsqrtf(v + 1e-5f) * og[k];
    sc[i] = scale;
    sh[i] = ob[k] - m * scale;
  }
  __syncthreads();
  const int N = BB * TT * 5;
  for (int i = blockIdx.x * 256 + tid; i < N; i += gridDim.x * 256) {
    int j = i % 320;
    outy[i] = fmaf(outy[i], sc[j], sh[j]);
  }
}

extern "C" void kernel_launch(void* const* d_in, const int* in_sizes, int n_in,
                              void* d_out, int out_size, void* d_ws, size_t ws_size,
                              hipStream_t stream) {
  const float* xin  = (const float*)d_in[0];
  const float* ing  = (const float*)d_in[1];
  const float* inb  = (const float*)d_in[2];
  const float* Wemb = (const float*)d_in[3];
  const float* bemb = (const float*)d_in[4];
  const float* eg   = (const float*)d_in[5];
  const float* eb   = (const float*)d_in[6];
  const float* Wih  = (const float*)d_in[7];
  const float* Whh  = (const float*)d_in[8];
  const float* bih  = (const float*)d_in[9];
  const float* bhh  = (const float*)d_in[10];
  const float* Wout = (const float*)d_in[11];
  const float* bout = (const float*)d_in[12];
  const float* og   = (const float*)d_in[13];
  const float* ob   = (const float*)d_in[14];

  float* ws    = (float*)d_ws;
  float* stats = ws;             // 320
  float* A0    = ws + 1024;      // 8192
  float* A1    = ws + 9216;      // 8192
  float* Ct    = ws + 17408;     // 8192
  float* bc    = ws + 25600;     // 512
  short* Wcb   = (short*)(ws + 26624);   // 131072 shorts (256 KB)
  short* Woutb = (short*)(ws + 92160);   // 2048 shorts (4 KB)
  float* ostp  = ws + 93184;     // 2560

  float* outy = (float*)d_out;
  float* hout = outy + (size_t)BB * TT * 5;
  float* cout = hout + (size_t)BB * 128;

  prep_stats_kernel<<<131, 256, 0, stream>>>(Wih, Whh, bih, bhh, Wout, Wcb, Woutb, bc,
                                             xin, stats);
  coef_kernel <<<1, 128, 0, stream>>>(stats, Wemb, bemb, ing, inb, eg, eb, A0, A1, Ct);
  lstm_kernel <<<256, 512, 0, stream>>>(xin, A0, A1, Ct, Wcb, bc, Woutb, bout,
                                        outy, hout, cout);
  ostats_kernel<<<256, 256, 0, stream>>>(outy, ostp);
  onorm_kernel <<<1024, 256, 0, stream>>>(outy, ostp, og, ob);
}

// Round 14
// 211.575 us; speedup vs baseline: 1.0675x; 1.0675x over previous
//
#include <hip/hip_runtime.h>
#include <hip/hip_bf16.h>

#define BB 8192
#define TT 64
#define L2E 1.44269504088896f
// dynamic LDS: tabs[24576 f32] (96 KB) + acts[32*512 bf16] (32 KB) + xs[32*128 f32] (16 KB)
#define LSTM_LDS_BYTES (98304 + 32768 + 16384)

typedef __attribute__((ext_vector_type(8))) short bf16x8;
typedef __attribute__((ext_vector_type(4))) float f32x4;

__device__ __forceinline__ float exp2g(float x) { return __builtin_amdgcn_exp2f(x); }
__device__ __forceinline__ float rcpg(float x)  { return __builtin_amdgcn_rcpf(x); }
__device__ __forceinline__ short f2bf_s(float x) {
  __hip_bfloat16 b = __float2bfloat16(x);
  return *reinterpret_cast<short*>(&b);
}
// acts[row][k], k in [0,512): e_buf0, e_buf1, h_buf0, h_buf1. 16B-granule XOR swizzle.
__device__ __forceinline__ int aidx(int row, int k) {
  return row * 512 + ((((k >> 3) ^ (row & 7))) << 3) + (k & 7);
}

// ---- 1+2. fused: weights -> bf16 B-fragments (exp2-prescaled) AND input moments ----
__global__ void prep_stats_kernel(const float* __restrict__ Wih, const float* __restrict__ Whh,
                                  const float* __restrict__ bih, const float* __restrict__ bhh,
                                  const float* __restrict__ Wout,
                                  short* __restrict__ Wcb, short* __restrict__ Woutb,
                                  float* __restrict__ bc,
                                  const float* __restrict__ x, float* __restrict__ stats) {
  if (blockIdx.x < 67) {
    int idx = blockIdx.x * 256 + threadIdx.x;   // 17152 total
    if (idx < 16384) {
      int l = idx & 63, f = idx >> 6;
      int kt = f >> 5, nt = f & 31;
      int k0 = kt * 32 + ((l >> 4) << 3);
      int col = nt * 16 + (l & 15);
      int gate = col >> 7;
      float s = (gate == 2) ? (2.f * L2E) : (-L2E);
      const float* src = (k0 < 128) ? (Wih + col * 128 + k0) : (Whh + col * 128 + (k0 - 128));
      bf16x8 v;
      #pragma unroll
      for (int e = 0; e < 8; e++) v[e] = f2bf_s(src[e] * s);
      *(bf16x8*)(Wcb + (size_t)idx * 8) = v;
    } else if (idx < 16640) {
      int i2 = idx - 16384;
      int l = i2 & 63, f = i2 >> 6;              // f = kyt
      int k0 = f * 32 + ((l >> 4) << 3);
      int col = l & 15;
      bf16x8 v;
      #pragma unroll
      for (int e = 0; e < 8; e++)
        v[e] = (col < 5) ? f2bf_s(Wout[col * 128 + k0 + e]) : (short)0;
      *(bf16x8*)(Woutb + (size_t)i2 * 8) = v;
    } else {
      int i3 = idx - 16640;
      int gate = i3 >> 7;
      float s = (gate == 2) ? (2.f * L2E) : (-L2E);
      bc[i3] = (bih[i3] + bhh[i3]) * s;
    }
  } else {
    int t = blockIdx.x - 67, tid = threadIdx.x;
    float s0=0, s1=0, s2=0, s3=0, s4=0;
    for (int b = tid; b < BB; b += 256) {
      const float* p = x + ((size_t)b * TT + t) * 2;
      float x0 = p[0], x1 = p[1];
      s0 += x0; s1 += x1; s2 += x0*x0; s3 += x0*x1; s4 += x1*x1;
    }
    __shared__ float red[4][5];
    int lane = tid & 63, w = tid >> 6;
    #pragma unroll
    for (int off = 32; off > 0; off >>= 1) {
      s0 += __shfl_down(s0, off); s1 += __shfl_down(s1, off);
      s2 += __shfl_down(s2, off); s3 += __shfl_down(s3, off); s4 += __shfl_down(s4, off);
    }
    if (lane == 0) { red[w][0]=s0; red[w][1]=s1; red[w][2]=s2; red[w][3]=s3; red[w][4]=s4; }
    __syncthreads();
    if (tid < 5) stats[t*5 + tid] = red[0][tid] + red[1][tid] + red[2][tid] + red[3][tid];
  }
}

// ---- 3. fold input-BN + embed Linear + per-step embed-BN into A0/A1/C ----
__global__ void coef_kernel(const float* __restrict__ stats,
                            const float* __restrict__ Wemb, const float* __restrict__ bemb,
                            const float* __restrict__ ing, const float* __restrict__ inb,
                            const float* __restrict__ eg, const float* __restrict__ eb,
                            float* __restrict__ A0, float* __restrict__ A1, float* __restrict__ Ct) {
  __shared__ float st[64][5];
  __shared__ float glob[4];
  int tid = threadIdx.x;  // 128
  for (int i = tid; i < 320; i += 128) st[i / 5][i % 5] = stats[i];
  __syncthreads();
  if (tid == 0) {
    float S0=0, S1=0, S00=0, S11=0;
    for (int t = 0; t < 64; t++) { S0+=st[t][0]; S1+=st[t][1]; S00+=st[t][2]; S11+=st[t][4]; }
    float inv_n = 1.f / (float)(BB * TT);
    float M0 = S0*inv_n, M1 = S1*inv_n;
    float V0 = S00*inv_n - M0*M0, V1 = S11*inv_n - M1*M1;
    float P0 = rsqrtf(V0 + 1e-5f) * ing[0];
    float P1 = rsqrtf(V1 + 1e-5f) * ing[1];
    glob[0]=P0; glob[1]=P1; glob[2]=inb[0]-M0*P0; glob[3]=inb[1]-M1*P1;
  }
  __syncthreads();
  float P0=glob[0], P1=glob[1], Q0=glob[2], Q1=glob[3];
  int j = tid;
  float w0 = Wemb[j*2], w1 = Wemb[j*2+1];
  float a0 = P0*w0, a1 = P1*w1;
  float cj = Q0*w0 + Q1*w1 + bemb[j];
  float gam = eg[j], bet = eb[j];
  float invB = 1.f / (float)BB;
  for (int t = 0; t < 64; t++) {
    float m0 = st[t][0]*invB, m1 = st[t][1]*invB;
    float v00 = st[t][2]*invB - m0*m0;
    float v01 = st[t][3]*invB - m0*m1;
    float v11 = st[t][4]*invB - m1*m1;
    float mean = a0*m0 + a1*m1 + cj;
    float var  = a0*a0*v00 + 2.f*a0*a1*v01 + a1*a1*v11;
    float G = rsqrtf(var + 1e-5f) * gam;
    A0[t*128 + j] = G * a0;
    A1[t*128 + j] = G * a1;
    Ct[t*128 + j] = G * cj + (bet - mean * G);
  }
}

// write e(t) for row er, granule cg, into e-buffer (t&1); tables from LDS
__device__ __forceinline__ void write_e(short* acts_s, const float* tabs,
                                        int t, int er, int cg, const float* xs) {
  const float* a0p = tabs + t*128 + cg*8;
  const float* a1p = tabs + 8192 + t*128 + cg*8;
  const float* ccp = tabs + 16384 + t*128 + cg*8;
  const float4 a0a = *(const float4*)a0p, a0b = *(const float4*)(a0p + 4);
  const float4 a1a = *(const float4*)a1p, a1b = *(const float4*)(a1p + 4);
  const float4 cta = *(const float4*)ccp, ctb = *(const float4*)(ccp + 4);
  float x0 = xs[er * 128 + t * 2], x1 = xs[er * 128 + t * 2 + 1];
  bf16x8 v;
  v[0] = f2bf_s(fmaxf(fmaf(a0a.x, x0, fmaf(a1a.x, x1, cta.x)), 0.f));
  v[1] = f2bf_s(fmaxf(fmaf(a0a.y, x0, fmaf(a1a.y, x1, cta.y)), 0.f));
  v[2] = f2bf_s(fmaxf(fmaf(a0a.z, x0, fmaf(a1a.z, x1, cta.z)), 0.f));
  v[3] = f2bf_s(fmaxf(fmaf(a0a.w, x0, fmaf(a1a.w, x1, cta.w)), 0.f));
  v[4] = f2bf_s(fmaxf(fmaf(a0b.x, x0, fmaf(a1b.x, x1, ctb.x)), 0.f));
  v[5] = f2bf_s(fmaxf(fmaf(a0b.y, x0, fmaf(a1b.y, x1, ctb.y)), 0.f));
  v[6] = f2bf_s(fmaxf(fmaf(a0b.z, x0, fmaf(a1b.z, x1, ctb.z)), 0.f));
  v[7] = f2bf_s(fmaxf(fmaf(a0b.w, x0, fmaf(a1b.w, x1, ctb.w)), 0.f));
  int gk = (t & 1) * 16 + cg;
  *(bf16x8*)&acts_s[er * 512 + ((gk ^ (er & 7)) << 3)] = v;
}

// ---- 4. MFMA recurrence: R12 base + LDS tables + split y-proj ----
__launch_bounds__(512, 1)
__global__ void lstm_kernel(const float* __restrict__ x,
                            const float* __restrict__ Atab,   // A0|A1|Ct contiguous, 24576 f32
                            const short* __restrict__ Wcb, const float* __restrict__ bc,
                            const short* __restrict__ Woutb, const float* __restrict__ bout,
                            float* __restrict__ outy, float* __restrict__ hout,
                            float* __restrict__ cout) {
  extern __shared__ __align__(16) char sm[];
  float* tabs   = (float*)sm;                       // [3][64][128] f32
  short* acts_s = (short*)(sm + 98304);             // [32][512] bf16, swizzled
  float* xs     = (float*)(sm + 98304 + 32768);     // [32][128] f32

  const int tid  = threadIdx.x;
  const int lane = tid & 63;
  const int w    = tid >> 6;        // wave 0..7 -> col slice w*16 of each gate
  const int row0 = blockIdx.x * 32;
  const int cl   = lane & 15;       // col within slice / C-tile col / A-frag row
  const int lq   = lane >> 4;       // lane quad
  const int er   = tid >> 4;        // e-writer row 0..31
  const int cg   = tid & 15;        // e-writer col granule

  // preload x (1024 float4) and tables (6144 float4) into LDS
  {
    const float4* src = (const float4*)(x + (size_t)row0 * 128);
    float4* dst = (float4*)xs;
    dst[tid]       = src[tid];
    dst[tid + 512] = src[tid + 512];
    const float4* tsrc = (const float4*)Atab;
    float4* tdst = (float4*)tabs;
    #pragma unroll
    for (int i = 0; i < 12; i++) tdst[tid + i * 512] = tsrc[tid + i * 512];
  }

  // per-gate scaled biases (acc init values)
  float bgs[4];
  #pragma unroll
  for (int g = 0; g < 4; g++) bgs[g] = bc[g * 128 + w * 16 + cl];
  const float bov = (cl < 5) ? bout[cl] : 0.f;

  // gate weights resident in VGPRs: 32 fragments = 128 VGPRs
  bf16x8 wreg[8][4];
  {
    const bf16x8* wptr = (const bf16x8*)Wcb;
    #pragma unroll
    for (int kt = 0; kt < 8; kt++)
      #pragma unroll
      for (int g = 0; g < 4; g++)
        wreg[kt][g] = wptr[(size_t)(kt * 32 + g * 8 + w) * 64 + lane];
  }
  bf16x8 wof[4];
  if ((w & 3) == 0) {               // waves 0 and 4 run the y-projection
    #pragma unroll
    for (int kyt = 0; kyt < 4; kyt++)
      wof[kyt] = *(const bf16x8*)(Woutb + (size_t)(kyt * 64 + lane) * 8);
  }

  __syncthreads();  // xs + tabs ready

  // init: e(0) -> e-buf 0; h(-1)=0 -> h-buf 1
  write_e(acts_s, tabs, 0, er, cg, xs);
  {
    bf16x8 z = (bf16x8)0;
    int gk = 32 + 16 + cg;          // h-buf 1
    *(bf16x8*)&acts_s[er * 512 + ((gk ^ (er & 7)) << 3)] = z;
  }

  f32x4 cstate[2] = {{0.f,0.f,0.f,0.f},{0.f,0.f,0.f,0.f}};
  float hl[2][4];

  #pragma unroll 1
  for (int t = 0; t < TT; t++) {
    __syncthreads();                 // step t-1 writes visible; all t-1 reads done
    const int ebuf = t & 1;          // e(t)
    const int hbuf = (t + 1) & 1;    // h(t-1)
    const bool do_y = ((w & 3) == 0) && (t > 0);

    // gates = [e(t) | h(t-1)] @ Wc — mt-major chains
    f32x4 acc[4][2];
    #pragma unroll
    for (int g = 0; g < 4; g++)
      #pragma unroll
      for (int mt = 0; mt < 2; mt++)
        acc[g][mt] = (f32x4){bgs[g], bgs[g], bgs[g], bgs[g]};

    #pragma unroll
    for (int kt = 0; kt < 8; kt++) {          // chain mt=0 (rows cl)
      int k = (kt < 4) ? (ebuf * 128 + (kt * 4 + lq) * 8)
                       : (256 + hbuf * 128 + ((kt - 4) * 4 + lq) * 8);
      bf16x8 a0 = *(const bf16x8*)&acts_s[aidx(cl, k)];
      #pragma unroll
      for (int g = 0; g < 4; g++)
        acc[g][0] = __builtin_amdgcn_mfma_f32_16x16x32_bf16(a0, wreg[kt][g], acc[g][0], 0, 0, 0);
    }
    #pragma unroll
    for (int kt = 0; kt < 8; kt++) {          // chain mt=1 (rows 16+cl)
      int k = (kt < 4) ? (ebuf * 128 + (kt * 4 + lq) * 8)
                       : (256 + hbuf * 128 + ((kt - 4) * 4 + lq) * 8);
      bf16x8 a1 = *(const bf16x8*)&acts_s[aidx(16 + cl, k)];
      #pragma unroll
      for (int g = 0; g < 4; g++)
        acc[g][1] = __builtin_amdgcn_mfma_f32_16x16x32_bf16(a1, wreg[kt][g], acc[g][1], 0, 0, 0);
    }

    // y(t-1) MFMAs: independent chain, issued into the gate-MFMA shadow; store deferred
    f32x4 ya = (f32x4){0.f, 0.f, 0.f, 0.f};
    if (do_y) {
      int mty = w >> 2;
      int row = mty * 16 + cl;
      #pragma unroll
      for (int kyt = 0; kyt < 4; kyt++) {
        int k = 256 + hbuf * 128 + (kyt * 4 + lq) * 8;
        bf16x8 ah = *(const bf16x8*)&acts_s[aidx(row, k)];
        ya = __builtin_amdgcn_mfma_f32_16x16x32_bf16(ah, wof[kyt], ya, 0, 0, 0);
      }
    }

    // dependency-free VALU: e(t+1) from LDS tables
    if (t < TT - 1)
      write_e(acts_s, tabs, t + 1, er, cg, xs);

    // elementwise LSTM update (lane-local), h(t) -> h-buf t&1
    #pragma unroll
    for (int mt = 0; mt < 2; mt++) {
      #pragma unroll
      for (int q = 0; q < 4; q++) {
        float Ei = exp2g(acc[0][mt][q]);          // e^{-i}
        float Ef = exp2g(acc[1][mt][q]);          // e^{-f}
        float Eg = exp2g(acc[2][mt][q]);          // e^{2g}
        float Eo = exp2g(acc[3][mt][q]);          // e^{-o}
        float di = 1.f + Ei, df = 1.f + Ef, dg = 1.f + Eg;
        float p  = di * dg;
        float num = fmaf(cstate[mt][q], p, (Eg - 1.f) * df);
        float cn  = num * rcpg(df * p);           // sig(f)*c + sig(i)*tanh(g)
        cstate[mt][q] = cn;
        float Ec = exp2g(cn * (2.f * L2E));       // e^{2c}
        float hn = (Ec - 1.f) * rcpg((1.f + Eo) * (1.f + Ec));  // sig(o)*tanh(c)
        hl[mt][q] = hn;
        int row = mt * 16 + lq * 4 + q;
        int k   = 256 + (t & 1) * 128 + w * 16 + cl;
        acts_s[aidx(row, k)] = f2bf_s(hn);
      }
    }

    // deferred y(t-1) store (ya long since complete)
    if (do_y) {
      int mty = w >> 2;
      if (cl < 5) {
        #pragma unroll
        for (int q = 0; q < 4; q++) {
          int brow = row0 + mty * 16 + lq * 4 + q;
          outy[((size_t)brow * TT + (t - 1)) * 5 + cl] = ya[q] + bov;
        }
      }
    }
  }

  __syncthreads();                   // h(TT-1) visible
  if ((w & 3) == 0) {                // final y(TT-1)
    int mty = w >> 2;
    int row = mty * 16 + cl;
    f32x4 ya = (f32x4){0.f,0.f,0.f,0.f};
    #pragma unroll
    for (int kyt = 0; kyt < 4; kyt++) {
      int k = 256 + ((TT - 1) & 1) * 128 + (kyt * 4 + lq) * 8;
      bf16x8 ah = *(const bf16x8*)&acts_s[aidx(row, k)];
      ya = __builtin_amdgcn_mfma_f32_16x16x32_bf16(ah, wof[kyt], ya, 0, 0, 0);
    }
    if (cl < 5) {
      #pragma unroll
      for (int q = 0; q < 4; q++) {
        int brow = row0 + mty * 16 + lq * 4 + q;
        outy[((size_t)brow * TT + (TT - 1)) * 5 + cl] = ya[q] + bov;
      }
    }
  }

  // final h, c
  #pragma unroll
  for (int mt = 0; mt < 2; mt++) {
    #pragma unroll
    for (int q = 0; q < 4; q++) {
      int brow = row0 + mt * 16 + lq * 4 + q;
      int col  = w * 16 + cl;
      hout[(size_t)brow * 128 + col] = hl[mt][q];
      cout[(size_t)brow * 128 + col] = cstate[mt][q];
    }
  }
}

// ---- 5. per-(t,k) output BN partial stats (256 blocks = full chip) ----
__global__ void ostats_kernel(const float* __restrict__ outy, float* __restrict__ ostp) {
  int t = blockIdx.x >> 2, part = blockIdx.x & 3;
  int tid = threadIdx.x;
  float s[5] = {0,0,0,0,0}, s2[5] = {0,0,0,0,0};
  int b0 = part * 2048;
  for (int b = b0 + tid; b < b0 + 2048; b += 256) {
    const float* p = outy + ((size_t)b * TT + t) * 5;
    #pragma unroll
    for (int k = 0; k < 5; k++) { float v = p[k]; s[k] += v; s2[k] += v*v; }
  }
  __shared__ float red[4][10];
  int lane = tid & 63, w = tid >> 6;
  #pragma unroll
  for (int off = 32; off > 0; off >>= 1) {
    #pragma unroll
    for (int k = 0; k < 5; k++) {
      s[k]  += __shfl_down(s[k], off);
      s2[k] += __shfl_down(s2[k], off);
    }
  }
  if (lane == 0) {
    #pragma unroll
    for (int k = 0; k < 5; k++) { red[w][k] = s[k]; red[w][5+k] = s2[k]; }
  }
  __syncthreads();
  if (tid < 10) ostp[blockIdx.x * 10 + tid] = red[0][tid]+red[1][tid]+red[2][tid]+red[3][tid];
}

// ---- 6. fused finalize + normalize: each block recomputes sc/sh in LDS ----
__global__ void onorm_kernel(float* __restrict__ outy, const float* __restrict__ ostp,
                             const float* __restrict__ og, const float* __restrict__ ob) {
  __shared__ float sc[320], sh[320];
  int tid = threadIdx.x;
  const float invB = 1.f / (float)BB;
  for (int i = tid; i < 320; i += 256) {
    int t = i / 5, k = i - t * 5;
    float m  = (ostp[(t*4+0)*10+k]   + ostp[(t*4+1)*10+k]   + ostp[(t*4+2)*10+k]   + ostp[(t*4+3)*10+k]) * invB;
    float s2 = (ostp[(t*4+0)*10+5+k] + ostp[(t*4+1)*10+5+k] + ostp[(t*4+2)*10+5+k] + ostp[(t*4+3)*10+5+k]) * invB;
    float v = s2 - m * m;
    float scale = rsqrtf(v + 1e-5f) * og[k];
    sc[i] = scale;
    sh[i] = ob[k] - m * scale;
  }
  __syncthreads();
  const int N = BB * TT * 5;
  for (int i = blockIdx.x * 256 + tid; i < N; i += gridDim.x * 256) {
    int j = i % 320;
    outy[i] = fmaf(outy[i], sc[j], sh[j]);
  }
}

extern "C" void kernel_launch(void* const* d_in, const int* in_sizes, int n_in,
                              void* d_out, int out_size, void* d_ws, size_t ws_size,
                              hipStream_t stream) {
  const float* xin  = (const float*)d_in[0];
  const float* ing  = (const float*)d_in[1];
  const float* inb  = (const float*)d_in[2];
  const float* Wemb = (const float*)d_in[3];
  const float* bemb = (const float*)d_in[4];
  const float* eg   = (const float*)d_in[5];
  const float* eb   = (const float*)d_in[6];
  const float* Wih  = (const float*)d_in[7];
  const float* Whh  = (const float*)d_in[8];
  const float* bih  = (const float*)d_in[9];
  const float* bhh  = (const float*)d_in[10];
  const float* Wout = (const float*)d_in[11];
  const float* bout = (const float*)d_in[12];
  const float* og   = (const float*)d_in[13];
  const float* ob   = (const float*)d_in[14];

  float* ws    = (float*)d_ws;
  float* stats = ws;             // 320
  float* A0    = ws + 1024;      // 8192  (A0|A1|Ct contiguous = 24576 floats)
  float* A1    = ws + 9216;      // 8192
  float* Ct    = ws + 17408;     // 8192
  float* bc    = ws + 25600;     // 512
  short* Wcb   = (short*)(ws + 26624);   // 131072 shorts (256 KB)
  short* Woutb = (short*)(ws + 92160);   // 2048 shorts (4 KB)
  float* ostp  = ws + 93184;     // 2560

  float* outy = (float*)d_out;
  float* hout = outy + (size_t)BB * TT * 5;
  float* cout = hout + (size_t)BB * 128;

  hipFuncSetAttribute((const void*)lstm_kernel,
                      hipFuncAttributeMaxDynamicSharedMemorySize, LSTM_LDS_BYTES);

  prep_stats_kernel<<<131, 256, 0, stream>>>(Wih, Whh, bih, bhh, Wout, Wcb, Woutb, bc,
                                             xin, stats);
  coef_kernel <<<1, 128, 0, stream>>>(stats, Wemb, bemb, ing, inb, eg, eb, A0, A1, Ct);
  lstm_kernel <<<256, 512, LSTM_LDS_BYTES, stream>>>(xin, A0, Wcb, bc, Woutb, bout,
                                                     outy, hout, cout);
  ostats_kernel<<<256, 256, 0, stream>>>(outy, ostp);
  onorm_kernel <<<1024, 256, 0, stream>>>(outy, ostp, og, ob);
}